// Round 7
// baseline (1254.462 us; speedup 1.0000x reference)
//
#include <hip/hip_runtime.h>
#include <stdint.h>

// ---------------- types ----------------
typedef short bf16x8 __attribute__((ext_vector_type(8)));
typedef float f32x16 __attribute__((ext_vector_type(16)));
typedef float f32x4  __attribute__((ext_vector_type(4)));
typedef float f32x2  __attribute__((ext_vector_type(2)));

#define NODES  2
#define LAYERS 4
#define HD     256
#define MTILE  128                // rows per block = 4 waves x 32 rows
#define QBYTES 32768              // one K-quarter of one layer: 256 n x 64 k x 2B
#define NQ     (NODES*LAYERS*4)   // 32 staged quarters

__device__ __forceinline__ unsigned short f2bf(float f) {  // RNE f32->bf16
  unsigned u = __float_as_uint(f);
  u += 0x7fffu + ((u >> 16) & 1u);
  return (unsigned short)(u >> 16);
}
__device__ __forceinline__ float bf2f(unsigned short s) {
  return __uint_as_float(((unsigned)s) << 16);
}
__device__ __forceinline__ float elu1(float v) {
  return v > 0.0f ? v : (__expf(v) - 1.0f);
}
__device__ __forceinline__ unsigned cvtpk(float lo, float hi) {  // low16=bf16(lo)
  unsigned r;
  asm("v_cvt_pk_bf16_f32 %0, %1, %2" : "=v"(r) : "v"(lo), "v"(hi));
  return r;
}
union U8 { bf16x8 v; unsigned u[4]; };

#define GLOAD_LDS16(gsrc, ldst)                                                        \
  __builtin_amdgcn_global_load_lds(                                                    \
      (const __attribute__((address_space(1))) unsigned int*)(gsrc),                   \
      (__attribute__((address_space(3))) unsigned int*)(ldst), 16, 0, 0)

// Blob layout (unchanged, conflict-free, zero-swizzle): per (node,layer) 4
// quarters of 32KB; quarter = [kc(4)][g(2)][nf(8)][l31(32)] x 16B fragments.
// kc stride inside a quarter = 8192B, so staging chunk p == kc-chunk p.
// Fragment element i holds k = 64*qq + 16*kc + 4*g + (i&3) + 8*(i>>2)
// (sigma permutation: D-frags feed next layer's B operand, no cross-lane ops).
__global__ __launch_bounds__(256) void convw_kernel(const float* __restrict__ w_hid,
                                                    unsigned short* __restrict__ blob) {
  int e = blockIdx.x * 256 + threadIdx.x;    // 0 .. 2*4*256*256-1
  int nl = e >> 16;                          // node*4+layer
  int k  = (e >> 8) & 255;
  int n  = e & 255;
  float v = w_hid[(nl * 256 + k) * 256 + n];
  int qq  = k >> 6;
  int kc  = (k >> 4) & 3;
  int k16 = k & 15;
  int g   = (k16 >> 2) & 1;
  int i   = (k16 & 3) | ((k16 >> 3) << 2);
  int nf  = n >> 5, l31 = n & 31;
  unsigned boff = ((unsigned)(nl * 4 + qq) << 15)
                + ((unsigned)kc << 13) + ((unsigned)g << 12)
                + ((unsigned)nf << 9) + ((unsigned)l31 << 4) + ((unsigned)i << 1);
  blob[boff >> 1] = f2bf(v);
}

// ---------------- main fused kernel ----------------
// 4 waves x 32 rows, 2 blocks/CU (2 waves/SIMD -> TLP). T3+T4 pipeline:
// 16 phases/layer, each {vmcnt(6); 8 ds_read; stage 1 chunk of quarter iq+1;
// 8 MFMA; s_barrier}. No vmcnt(0) drain in the main loop; chunk p of quarter
// iq is consumed 4 phases after issue, always exactly 7th-newest -> vmcnt(6).
__global__ __launch_bounds__(256, 2) void nld_kernel(
    const float* __restrict__ uv, const float* __restrict__ w_in,
    const float* __restrict__ b_in, const float* __restrict__ b_hid,
    const float* __restrict__ w_out, const float* __restrict__ b_out,
    const unsigned short* __restrict__ blob, float* __restrict__ out, int nrows) {

  __shared__ __attribute__((aligned(16))) char  w_sm[2][QBYTES];   // 64KB dbuf
  __shared__ __attribute__((aligned(16))) float pb_hid[NODES * LAYERS * HD]; // 8KB
  __shared__ __attribute__((aligned(16))) float pb_in[NODES * HD];           // 2KB

  const int t    = threadIdx.x;
  const int lane = t & 63;
  const int wv   = t >> 6;        // 0..3
  const int l31  = lane & 31;
  const int g    = lane >> 5;
  const long row = (long)blockIdx.x * MTILE + wv * 32 + l31;

  auto stage_chunk = [&](int iq, int buf, int p) {   // 8KB kc-chunk, 2 loads/thread
    const char* src = (const char*)blob + (size_t)iq * QBYTES + p * 8192 + t * 16;
    char* dst = &w_sm[buf][p * 8192 + t * 16];
    GLOAD_LDS16(src, dst);
    GLOAD_LDS16(src + 4096, dst + 4096);
  };

  // prologue: stage full quarter 0, params; one full drain via __syncthreads
#pragma unroll
  for (int p = 0; p < 4; ++p) stage_chunk(0, 0, p);
  for (int i = t; i < NODES * LAYERS * HD; i += 256) pb_hid[i] = b_hid[i];
  for (int i = t; i < NODES * HD; i += 256) pb_in[i] = b_in[i];

  float x0 = 0.0f, x1 = 0.0f;
  if (row < nrows) { f32x2 u = *(const f32x2*)(uv + row * 2); x0 = u[0]; x1 = u[1]; }
  __syncthreads();   // quarter 0 + params visible

  bf16x8 hb[16];
  const unsigned fbase = (unsigned)(g * 4096 + l31 * 16);

  for (int nd = 0; nd < NODES; ++nd) {
    // ---- input layer: build hb directly (lane computes exactly its k-set)
    {
      const float* wi0 = w_in + nd * 2 * HD;
      const float* wi1 = wi0 + HD;
      const float* bi  = &pb_in[nd * HD];
#pragma unroll
      for (int c = 0; c < 16; ++c) {
        int kb = 16 * c + 4 * g;
        f32x4 a0 = *(const f32x4*)(wi0 + kb);
        f32x4 a1 = *(const f32x4*)(wi0 + kb + 8);
        f32x4 c0 = *(const f32x4*)(wi1 + kb);
        f32x4 c1 = *(const f32x4*)(wi1 + kb + 8);
        f32x4 e0 = *(const f32x4*)(bi + kb);
        f32x4 e1 = *(const f32x4*)(bi + kb + 8);
        float v0 = elu1(fmaf(x1, c0[0], fmaf(x0, a0[0], e0[0])));
        float v1 = elu1(fmaf(x1, c0[1], fmaf(x0, a0[1], e0[1])));
        float v2 = elu1(fmaf(x1, c0[2], fmaf(x0, a0[2], e0[2])));
        float v3 = elu1(fmaf(x1, c0[3], fmaf(x0, a0[3], e0[3])));
        float v4 = elu1(fmaf(x1, c1[0], fmaf(x0, a1[0], e1[0])));
        float v5 = elu1(fmaf(x1, c1[1], fmaf(x0, a1[1], e1[1])));
        float v6 = elu1(fmaf(x1, c1[2], fmaf(x0, a1[2], e1[2])));
        float v7 = elu1(fmaf(x1, c1[3], fmaf(x0, a1[3], e1[3])));
        U8 p;
        p.u[0] = cvtpk(v0, v1); p.u[1] = cvtpk(v2, v3);
        p.u[2] = cvtpk(v4, v5); p.u[3] = cvtpk(v6, v7);
        hb[c] = p.v;
      }
    }

    // ---- 4 hidden layers: 16 counted-vmcnt phases each
    for (int ly = 0; ly < LAYERS; ++ly) {
      const float* bl = &pb_hid[(nd * LAYERS + ly) * HD];
      f32x16 acc[8];
#pragma unroll
      for (int nf = 0; nf < 8; ++nf) {        // acc init = bias
        int nb = 32 * nf + 4 * g;
        f32x4 b0 = *(const f32x4*)(bl + nb);
        f32x4 b1 = *(const f32x4*)(bl + nb + 8);
        f32x4 b2 = *(const f32x4*)(bl + nb + 16);
        f32x4 b3 = *(const f32x4*)(bl + nb + 24);
#pragma unroll
        for (int j = 0; j < 4; ++j) {
          acc[nf][j]      = b0[j];
          acc[nf][4 + j]  = b1[j];
          acc[nf][8 + j]  = b2[j];
          acc[nf][12 + j] = b3[j];
        }
      }

      const int iq0 = (nd * LAYERS + ly) * 4;
#pragma unroll
      for (int qq = 0; qq < 4; ++qq) {
        int iq  = iq0 + qq;
        int nq1 = (iq + 1 < NQ) ? iq + 1 : NQ - 1;   // dummy tail keeps vmcnt math
        int b1  = (iq + 1) & 1;
        const char* wb = &w_sm[iq & 1][0] + fbase;
#pragma unroll
        for (int p = 0; p < 4; ++p) {
          // chunk p of quarter iq is 7th-newest outstanding load here
          asm volatile("s_waitcnt vmcnt(6)" ::: "memory");
          __builtin_amdgcn_sched_barrier(0);
          bf16x8 wf0 = *(const bf16x8*)(wb + p * 8192 + 0 * 512);
          bf16x8 wf1 = *(const bf16x8*)(wb + p * 8192 + 1 * 512);
          bf16x8 wf2 = *(const bf16x8*)(wb + p * 8192 + 2 * 512);
          bf16x8 wf3 = *(const bf16x8*)(wb + p * 8192 + 3 * 512);
          bf16x8 wf4 = *(const bf16x8*)(wb + p * 8192 + 4 * 512);
          bf16x8 wf5 = *(const bf16x8*)(wb + p * 8192 + 5 * 512);
          bf16x8 wf6 = *(const bf16x8*)(wb + p * 8192 + 6 * 512);
          bf16x8 wf7 = *(const bf16x8*)(wb + p * 8192 + 7 * 512);
          stage_chunk(nq1, b1, p);                   // prefetch, 4 phases ahead
          bf16x8 h = hb[4 * qq + p];
          __builtin_amdgcn_s_setprio(1);
          acc[0] = __builtin_amdgcn_mfma_f32_32x32x16_bf16(wf0, h, acc[0], 0, 0, 0);
          acc[1] = __builtin_amdgcn_mfma_f32_32x32x16_bf16(wf1, h, acc[1], 0, 0, 0);
          acc[2] = __builtin_amdgcn_mfma_f32_32x32x16_bf16(wf2, h, acc[2], 0, 0, 0);
          acc[3] = __builtin_amdgcn_mfma_f32_32x32x16_bf16(wf3, h, acc[3], 0, 0, 0);
          acc[4] = __builtin_amdgcn_mfma_f32_32x32x16_bf16(wf4, h, acc[4], 0, 0, 0);
          acc[5] = __builtin_amdgcn_mfma_f32_32x32x16_bf16(wf5, h, acc[5], 0, 0, 0);
          acc[6] = __builtin_amdgcn_mfma_f32_32x32x16_bf16(wf6, h, acc[6], 0, 0, 0);
          acc[7] = __builtin_amdgcn_mfma_f32_32x32x16_bf16(wf7, h, acc[7], 0, 0, 0);
          __builtin_amdgcn_s_setprio(0);
          __builtin_amdgcn_s_barrier();              // phase fence (keeps WAR safe)
        }
      }

      // ---- transform: acc -> hb (ELU + cvt_pk) — bias already in acc
#pragma unroll
      for (int nf = 0; nf < 8; ++nf) {
        float e[16];
#pragma unroll
        for (int j = 0; j < 16; ++j) e[j] = elu1(acc[nf][j]);
        U8 p, q;
        p.u[0] = cvtpk(e[0],  e[1]);  p.u[1] = cvtpk(e[2],  e[3]);
        p.u[2] = cvtpk(e[4],  e[5]);  p.u[3] = cvtpk(e[6],  e[7]);
        q.u[0] = cvtpk(e[8],  e[9]);  q.u[1] = cvtpk(e[10], e[11]);
        q.u[2] = cvtpk(e[12], e[13]); q.u[3] = cvtpk(e[14], e[15]);
        hb[2 * nf]     = p.v;
        hb[2 * nf + 1] = q.v;
      }
    }

    // ---- output layer: x += h @ w_out + b_out (reg h, broadcast w_out loads)
    {
      const float* wo = w_out + nd * HD * 2;
      float s0 = 0.0f, s1 = 0.0f;
#pragma unroll
      for (int c = 0; c < 16; ++c) {
        int kb = 16 * c + 4 * g;
        f32x4 wA0 = *(const f32x4*)(wo + kb * 2);
        f32x4 wA1 = *(const f32x4*)(wo + kb * 2 + 4);
        f32x4 wB0 = *(const f32x4*)(wo + (kb + 8) * 2);
        f32x4 wB1 = *(const f32x4*)(wo + (kb + 8) * 2 + 4);
        bf16x8 hv = hb[c];
        float f0 = bf2f((unsigned short)hv[0]), f1 = bf2f((unsigned short)hv[1]);
        float f2 = bf2f((unsigned short)hv[2]), f3 = bf2f((unsigned short)hv[3]);
        float f4 = bf2f((unsigned short)hv[4]), f5 = bf2f((unsigned short)hv[5]);
        float f6 = bf2f((unsigned short)hv[6]), f7 = bf2f((unsigned short)hv[7]);
        s0 = fmaf(f0, wA0[0], s0); s1 = fmaf(f0, wA0[1], s1);
        s0 = fmaf(f1, wA0[2], s0); s1 = fmaf(f1, wA0[3], s1);
        s0 = fmaf(f2, wA1[0], s0); s1 = fmaf(f2, wA1[1], s1);
        s0 = fmaf(f3, wA1[2], s0); s1 = fmaf(f3, wA1[3], s1);
        s0 = fmaf(f4, wB0[0], s0); s1 = fmaf(f4, wB0[1], s1);
        s0 = fmaf(f5, wB0[2], s0); s1 = fmaf(f5, wB0[3], s1);
        s0 = fmaf(f6, wB1[0], s0); s1 = fmaf(f6, wB1[1], s1);
        s0 = fmaf(f7, wB1[2], s0); s1 = fmaf(f7, wB1[3], s1);
      }
      s0 += __shfl_xor(s0, 32);
      s1 += __shfl_xor(s1, 32);
      x0 += s0 + b_out[nd * 2 + 0];
      x1 += s1 + b_out[nd * 2 + 1];
    }
  }

  if (row < nrows && g == 0) {
    f32x2 r; r[0] = x0; r[1] = x1;
    *(f32x2*)(out + row * 2) = r;
  }
}

// ---------------- launcher ----------------
extern "C" void kernel_launch(void* const* d_in, const int* in_sizes, int n_in,
                              void* d_out, int out_size, void* d_ws, size_t ws_size,
                              hipStream_t stream) {
  const float* uv    = (const float*)d_in[0];
  const float* w_in  = (const float*)d_in[1];
  const float* b_in  = (const float*)d_in[2];
  const float* w_hid = (const float*)d_in[3];
  const float* b_hid = (const float*)d_in[4];
  const float* w_out = (const float*)d_in[5];
  const float* b_out = (const float*)d_in[6];
  unsigned short* blob = (unsigned short*)d_ws;   // 1 MB bf16 permuted blob

  int whid_elems = in_sizes[3];                   // 524288
  convw_kernel<<<whid_elems / 256, 256, 0, stream>>>(w_hid, blob);

  int N = in_sizes[0] / 2;                        // 1048576 rows
  int grid = (N + MTILE - 1) / MTILE;             // 8192
  nld_kernel<<<grid, 256, 0, stream>>>(uv, w_in, b_in, b_hid, w_out, b_out,
                                       blob, (float*)d_out, N);
}